// Round 8
// baseline (728.523 us; speedup 1.0000x reference)
//
#include <hip/hip_runtime.h>
#include <math.h>

// Sizes (fixed by the problem)
#define VOCAB 50000
#define EDIM  200
#define HDIM  256
#define G3    768      // 3*H
#define NSEQ1 4096     // B*R*S word sequences
#define T1    32       // W
#define NSEQ2 256      // B*R sentence sequences
#define T2    16       // S
#define NSEQ3 16       // B review sequences
#define T3    16       // R

using bf16x8 = __attribute__((ext_vector_type(8))) short;
using f32x4  = __attribute__((ext_vector_type(4))) float;

__device__ __forceinline__ float sigmoid_f(float x) {
    return 1.0f / (1.0f + __expf(-x));
}
__device__ __forceinline__ float tanh_f(float x) {
    return 1.0f - 2.0f / (__expf(2.0f * x) + 1.0f);
}
// f32 -> bf16 (RNE)
__device__ __forceinline__ short f2b(float f) {
    unsigned u = __float_as_uint(f);
    unsigned r = (u + 0x7fffu + ((u >> 16) & 1u)) >> 16;
    return (short)r;
}
__device__ __forceinline__ float b2f(unsigned short v) {
    return __uint_as_float((unsigned)v << 16);
}
// barrier that drains ONLY lgkmcnt (LDS) — leaves global loads in flight
__device__ __forceinline__ void lds_barrier() {
    asm volatile("s_waitcnt lgkmcnt(0)\n\ts_barrier" ::: "memory");
}

// ---------------------------------------------------------------------------
// Batched f32 -> bf16 conversions (zero-padded): one launch for all 6 weights.
// ---------------------------------------------------------------------------
struct CvtJob { const float* src; short* dst; int kin; int kpad; };
struct CvtJobs { CvtJob j[6]; };

__global__ void convert6(CvtJobs jobs) {
    const CvtJob jb = jobs.j[blockIdx.y];
    const int r = blockIdx.x;
    for (int k = threadIdx.x; k < jb.kpad; k += blockDim.x)
        jb.dst[(size_t)r * jb.kpad + k] =
            (k < jb.kin) ? f2b(jb.src[(size_t)r * jb.kin + k]) : (short)0;
}

// ---------------------------------------------------------------------------
// C[M,768] = A[M,Keff] @ WB[768,KPAD]^T + bias  via bf16 MFMA, output written
// as bf16 in GATE-INTERLEAVED layout: row-stride 768 u16; within a row,
// element for global col c (c = g*256 + tt*16 + lr, pair pp=tt>>1, ti=tt&1)
// lives at u16 offset pp*96 + lr*6 + g*2 + ti. A lane's 6 GRU gather values
// (3 gates x 2 cols) are then 12 contiguous bytes.
// Block 512 (8 waves), wave = M-tile, 12 N-tiles. grid (ceil(M/128), 4).
// ---------------------------------------------------------------------------
template <int KC, bool AF32>
__global__ __launch_bounds__(512) void gemm_mfma(
    const void* __restrict__ Av, const short* __restrict__ WB,
    const float* __restrict__ bias, unsigned* __restrict__ Cv,
    int M, int Keff) {
    constexpr int KPAD  = KC * 32;
    constexpr int CELLS = KPAD / 8;
    __shared__ short As[128 * 256];          // 64 KB
    const int tid = threadIdx.x;
    const int m0 = blockIdx.x * 128;
    const int n0 = blockIdx.y * 192;

    {
        const int row  = tid >> 2;
        const int c0   = (tid & 3) * 8;
        const int rowg = m0 + row;
        const int vcell = Keff >> 3;
        for (int i = 0; i < 8; i++) {
            const int c = c0 + i;
            if (c >= CELLS) break;
            bf16x8 v;
            if (rowg < M && c < vcell) {
                if constexpr (AF32) {
                    const float* ap = (const float*)Av + (size_t)rowg * Keff + c * 8;
                    const float4 x = *(const float4*)ap;
                    const float4 y = *(const float4*)(ap + 4);
                    v[0] = f2b(x.x); v[1] = f2b(x.y); v[2] = f2b(x.z); v[3] = f2b(x.w);
                    v[4] = f2b(y.x); v[5] = f2b(y.y); v[6] = f2b(y.z); v[7] = f2b(y.w);
                } else {
                    const short* ap = (const short*)Av + (size_t)rowg * Keff + c * 8;
                    v = *(const bf16x8*)ap;
                }
            } else {
                v = (bf16x8)(short)0;
            }
            *(bf16x8*)&As[row * 256 + ((c ^ (row & 7)) << 3)] = v;
        }
    }
    __syncthreads();

    const int w  = tid >> 6;
    const int l  = tid & 63;
    const int lr = l & 15, lg = l >> 4;

    bf16x8 af[KC];
    {
        const int row = (w << 4) + lr;
#pragma unroll
        for (int kc = 0; kc < KC; kc++) {
            const int cell = kc * 4 + lg;
            af[kc] = *(const bf16x8*)&As[row * 256 + ((cell ^ (row & 7)) << 3)];
        }
    }
    f32x4 acc[12];
#pragma unroll
    for (int nt = 0; nt < 12; nt++) acc[nt] = (f32x4){0.f, 0.f, 0.f, 0.f};
#pragma unroll
    for (int nt = 0; nt < 12; nt++) {
        const short* wb = WB + (size_t)(n0 + nt * 16 + lr) * KPAD + lg * 8;
#pragma unroll
        for (int kc = 0; kc < KC; kc++) {
            bf16x8 bf = *(const bf16x8*)(wb + kc * 32);
            acc[nt] = __builtin_amdgcn_mfma_f32_16x16x32_bf16(af[kc], bf, acc[nt], 0, 0, 0);
        }
    }
    // epilogue: D col=lane&15 (=lr), row=(lane>>4)*4+q; pack nt-pairs to u32
    const int by12 = blockIdx.y * 12;
#pragma unroll
    for (int nt = 0; nt < 12; nt += 2) {
        const int gt = by12 + nt;            // even
        const int g  = gt >> 4;
        const int pp = (gt & 15) >> 1;
        const int uoff = pp * 48 + lr * 3 + g;    // u32 offset within row (384)
        const float bv0 = bias[n0 + nt * 16 + lr];
        const float bv1 = bias[n0 + (nt + 1) * 16 + lr];
#pragma unroll
        for (int q = 0; q < 4; q++) {
            const int row = m0 + (w << 4) + lg * 4 + q;
            if (row < M) {
                const unsigned lo = (unsigned short)f2b(acc[nt][q] + bv0);
                const unsigned hi = (unsigned short)f2b(acc[nt + 1][q] + bv1);
                Cv[(size_t)row * 384 + uoff] = lo | (hi << 16);
            }
        }
    }
}

// ---------------------------------------------------------------------------
// MFMA GRU, TM=16 seqs/block, block 512 (8 waves), 1 block/CU.
// Wave w owns 32 h-columns jj0=w*32+lr, jj1=jj0+16.
// r,z weights register(AGPR)-resident; n-gate weights LDS-resident (131 KB).
// h: f32 in regs; bf16 mirror DOUBLE-BUFFERED in swizzled LDS (hs0/hs1) ->
// ONE lgkm-only barrier per step (phase overlap across waves).
// gx rows are bf16 GATE-INTERLEAVED (see gemm): per q one dwordx3 gather,
// register double-buffered one step ahead (loads stay in flight across
// barriers; vmcnt never drained by the barrier).
// Optional fused MLP head (mW1!=null): selu(h@W1^T+b1)@W2^T+b2 -> mOut[n0+s].
// ---------------------------------------------------------------------------
__global__ __launch_bounds__(512, 2) void gru_mfma(
    const int* __restrict__ idx,        // null => dense rows (n0+s)*T + t
    const short* __restrict__ gxb,      // bf16 interleaved row table, stride 768
    const short* __restrict__ WB,       // [768][256] bf16 (linear)
    const float* __restrict__ bhh,
    short* __restrict__ hb16,           // optional [N][256] linear bf16 out
    const float* __restrict__ mW1,      // optional MLP
    const float* __restrict__ mb1,
    const float* __restrict__ mW2,
    const float* __restrict__ mb2,
    float* __restrict__ mOut,
    int T) {
    __shared__ __align__(16) short wsN[256 * 256];   // 131072 B, n-gate weights
    __shared__ __align__(16) short hs0[16 * 256];    // 8 KB
    __shared__ __align__(16) short hs1[16 * 256];    // 8 KB
    __shared__ int idxs[16 * T1];                    // 2 KB
    const int tid = threadIdx.x;
    const int n0 = blockIdx.x * 16;
    const int w  = tid >> 6, l = tid & 63;
    const int lr = l & 15, lg = l >> 4;
    const int jj0 = w * 32 + lr;
    const int jj1 = jj0 + 16;

    // ---- prologue ----
    for (int i = tid; i < 16 * 256; i += 512) hs0[i] = 0;
    if (idx) {
        for (int i = tid; i < 16 * T; i += 512) {
            const int s = i / T, p = i - s * T;
            int tk = idx[(size_t)(n0 + s) * T + p];
            idxs[s * T + p] = min(max(tk, 0), VOCAB - 1);
        }
    }
#pragma unroll
    for (int i = 0; i < 16; i++) {
        const int cellidx = tid * 16 + i;     // 0..8191
        const int rr = cellidx >> 5;          // 0..255
        const int cc = cellidx & 31;
        bf16x8 v = *(const bf16x8*)&WB[(size_t)(512 + rr) * 256 + cc * 8];
        *(bf16x8*)&wsN[rr * 256 + ((cc ^ (rr & 7)) << 3)] = v;
    }
    // r,z weights -> registers (128 regs), loaded once
    bf16x8 bwR[2][8], bwZ[2][8];
#pragma unroll
    for (int ti = 0; ti < 2; ti++) {
        const int jjt = (w * 2 + ti) * 16 + lr;
#pragma unroll
        for (int kc = 0; kc < 8; kc++) {
            bwR[ti][kc] = *(const bf16x8*)&WB[(size_t)jjt * 256 + kc * 32 + lg * 8];
            bwZ[ti][kc] = *(const bf16x8*)&WB[(size_t)(256 + jjt) * 256 + kc * 32 + lg * 8];
        }
    }
    const float bR0 = bhh[jj0],       bR1 = bhh[jj1];
    const float bZ0 = bhh[256 + jj0], bZ1 = bhh[256 + jj1];
    const float bN0 = bhh[512 + jj0], bN1 = bhh[512 + jj1];

    float hreg[2][4] = {};
    __syncthreads();   // prologue drain (once)

    // gather: per step 4 x dwordx3 (interleaved layout), reg double-buffered
    uint3 gA[4], gB[4];
    auto load_gx = [&](uint3 (&buf)[4], int t) {
#pragma unroll
        for (int q = 0; q < 4; q++) {
            const int s = lg * 4 + q;
            size_t rowbase;
            if (idx) rowbase = (size_t)idxs[s * T + t] * G3;
            else     rowbase = ((size_t)(n0 + s) * T + t) * G3;
            buf[q] = *(const uint3*)(gxb + rowbase + w * 96 + lr * 6);
        }
    };

    auto step = [&](const uint3 (&buf)[4], const short* hsR, short* hsW) {
        f32x4 aR[2], aZ[2], aN[2];
#pragma unroll
        for (int ti = 0; ti < 2; ti++) {
            aR[ti] = (f32x4){0.f, 0.f, 0.f, 0.f};
            aZ[ti] = (f32x4){0.f, 0.f, 0.f, 0.f};
            aN[ti] = (f32x4){0.f, 0.f, 0.f, 0.f};
        }
#pragma unroll
        for (int kc = 0; kc < 8; kc++) {
            const int cell = kc * 4 + lg;
            const bf16x8 a   = *(const bf16x8*)&hsR[lr * 256 + ((cell ^ (lr & 7)) << 3)];
            const bf16x8 n0f = *(const bf16x8*)&wsN[jj0 * 256 + ((cell ^ (jj0 & 7)) << 3)];
            const bf16x8 n1f = *(const bf16x8*)&wsN[jj1 * 256 + ((cell ^ (jj1 & 7)) << 3)];
            aR[0] = __builtin_amdgcn_mfma_f32_16x16x32_bf16(a, bwR[0][kc], aR[0], 0, 0, 0);
            aZ[0] = __builtin_amdgcn_mfma_f32_16x16x32_bf16(a, bwZ[0][kc], aZ[0], 0, 0, 0);
            aN[0] = __builtin_amdgcn_mfma_f32_16x16x32_bf16(a, n0f, aN[0], 0, 0, 0);
            aR[1] = __builtin_amdgcn_mfma_f32_16x16x32_bf16(a, bwR[1][kc], aR[1], 0, 0, 0);
            aZ[1] = __builtin_amdgcn_mfma_f32_16x16x32_bf16(a, bwZ[1][kc], aZ[1], 0, 0, 0);
            aN[1] = __builtin_amdgcn_mfma_f32_16x16x32_bf16(a, n1f, aN[1], 0, 0, 0);
        }
        // phase B (no barrier before: hsW != hsR, wsN read-only)
#pragma unroll
        for (int q = 0; q < 4; q++) {
            const int s = lg * 4 + q;
            const uint3 u = buf[q];
            {   // triple 0 (lo halves)
                const float xr = b2f((unsigned short)(u.x & 0xffff));
                const float xz = b2f((unsigned short)(u.y & 0xffff));
                const float xn = b2f((unsigned short)(u.z & 0xffff));
                const float r = sigmoid_f(xr + aR[0][q] + bR0);
                const float z = sigmoid_f(xz + aZ[0][q] + bZ0);
                const float n = tanh_f(xn + r * (aN[0][q] + bN0));
                const float h = (1.f - z) * n + z * hreg[0][q];
                hreg[0][q] = h;
                hsW[s * 256 + (((jj0 >> 3) ^ (s & 7)) << 3) + (jj0 & 7)] = f2b(h);
            }
            {   // triple 1 (hi halves)
                const float xr = b2f((unsigned short)(u.x >> 16));
                const float xz = b2f((unsigned short)(u.y >> 16));
                const float xn = b2f((unsigned short)(u.z >> 16));
                const float r = sigmoid_f(xr + aR[1][q] + bR1);
                const float z = sigmoid_f(xz + aZ[1][q] + bZ1);
                const float n = tanh_f(xn + r * (aN[1][q] + bN1));
                const float h = (1.f - z) * n + z * hreg[1][q];
                hreg[1][q] = h;
                hsW[s * 256 + (((jj1 >> 3) ^ (s & 7)) << 3) + (jj1 & 7)] = f2b(h);
            }
        }
        lds_barrier();   // single barrier/step: writes visible for next reads
    };

    load_gx(gA, 0);
    for (int t = 0; t < T; t += 2) {
        if (t + 1 < T) load_gx(gB, t + 1);
        step(gA, hs0, hs1);
        if (t + 2 < T) load_gx(gA, t + 2);
        step(gB, hs1, hs0);
    }

    // ---- epilogue: optional linear bf16 h out ----
    if (hb16) {
#pragma unroll
        for (int q = 0; q < 4; q++) {
            const int s = lg * 4 + q;
            hb16[(size_t)(n0 + s) * HDIM + jj0] = f2b(hreg[0][q]);
            hb16[(size_t)(n0 + s) * HDIM + jj1] = f2b(hreg[1][q]);
        }
    }
    // ---- fused MLP head (wsN and hs0 re-used as scratch) ----
    if (mW1) {
        float* hf = (float*)wsN;             // [16][256] f32
#pragma unroll
        for (int q = 0; q < 4; q++) {
            const int s = lg * 4 + q;
            hf[s * HDIM + jj0] = hreg[0][q];
            hf[s * HDIM + jj1] = hreg[1][q];
        }
        lds_barrier();
        const int mm = tid & 127;
        const int sg = tid >> 7;             // 0..3
        const float* w1 = mW1 + (size_t)mm * HDIM;
        const float b1v = mb1[mm];
        const float w2v = mW2[mm];
        float* redf = (float*)hs0;           // [16][128] f32
#pragma unroll
        for (int si = 0; si < 4; si++) {
            const int s = si * 4 + sg;
            const float* hrow = hf + s * HDIM;
            float d = 0.f;
#pragma unroll 4
            for (int k = 0; k < HDIM; k += 4) {
                const float4 a = *(const float4*)&hrow[k];
                const float4 b = *(const float4*)&w1[k];
                d += a.x * b.x; d += a.y * b.y; d += a.z * b.z; d += a.w * b.w;
            }
            d += b1v;
            const float alpha = 1.6732632423543772f;
            const float scale = 1.0507009873554805f;
            const float sv = scale * (d > 0.f ? d : alpha * expm1f(d));
            redf[s * 128 + mm] = sv * w2v;
        }
        lds_barrier();
        if (tid < 16) {
            float accv = mb2[0];
            for (int m = 0; m < 128; m++) accv += redf[tid * 128 + m];
            mOut[n0 + tid] = accv;
        }
    }
}

// ---------------------------------------------------------------------------
extern "C" void kernel_launch(void* const* d_in, const int* in_sizes, int n_in,
                              void* d_out, int out_size, void* d_ws, size_t ws_size,
                              hipStream_t stream) {
    const int*   idx    = (const int*)d_in[0];
    const float* emb    = (const float*)d_in[1];
    const float* w_Wih  = (const float*)d_in[2];
    const float* w_Whh  = (const float*)d_in[3];
    const float* w_bih  = (const float*)d_in[4];
    const float* w_bhh  = (const float*)d_in[5];
    const float* s_Wih  = (const float*)d_in[6];
    const float* s_Whh  = (const float*)d_in[7];
    const float* s_bih  = (const float*)d_in[8];
    const float* s_bhh  = (const float*)d_in[9];
    const float* r_Wih  = (const float*)d_in[10];
    const float* r_Whh  = (const float*)d_in[11];
    const float* r_bih  = (const float*)d_in[12];
    const float* r_bhh  = (const float*)d_in[13];
    const float* rfc_W1 = (const float*)d_in[14];
    const float* rfc_b1 = (const float*)d_in[15];
    const float* rfc_W2 = (const float*)d_in[16];
    const float* rfc_b2 = (const float*)d_in[17];
    const float* pfc_W1 = (const float*)d_in[18];
    const float* pfc_b1 = (const float*)d_in[19];
    const float* pfc_W2 = (const float*)d_in[20];
    const float* pfc_b2 = (const float*)d_in[21];

    float* out = (float*)d_out;      // [0..15] b_stars, [16..271] r_stars

    // ---- workspace layout ----
    short* sws = (short*)d_ws;
    short* Pb      = sws;                                  // 50000*768 bf16 (interleaved)
    short* gx2b    = Pb      + (size_t)VOCAB * G3;         // 4096*768 (interleaved)
    short* gx3b    = gx2b    + (size_t)NSEQ1 * G3;         // 256*768 (interleaved)
    short* WhhB_w  = gx3b    + (size_t)NSEQ2 * G3;         // 768*256
    short* WihB_w  = WhhB_w  + (size_t)G3 * HDIM;          // 768*224
    short* sWihB   = WihB_w  + (size_t)G3 * 224;
    short* sWhhB   = sWihB   + (size_t)G3 * HDIM;
    short* rWihB   = sWhhB   + (size_t)G3 * HDIM;
    short* rWhhB   = rWihB   + (size_t)G3 * HDIM;
    short* sent_hB = rWhhB   + (size_t)G3 * HDIM;          // 4096*256 linear
    short* rev_hB  = sent_hB + (size_t)NSEQ1 * HDIM;       // 256*256 linear

    // ---- weight conversions: one launch ----
    CvtJobs jobs;
    jobs.j[0] = {w_Whh, WhhB_w, HDIM, HDIM};
    jobs.j[1] = {w_Wih, WihB_w, EDIM, 224};
    jobs.j[2] = {s_Wih, sWihB, HDIM, HDIM};
    jobs.j[3] = {s_Whh, sWhhB, HDIM, HDIM};
    jobs.j[4] = {r_Wih, rWihB, HDIM, HDIM};
    jobs.j[5] = {r_Whh, rWhhB, HDIM, HDIM};
    convert6<<<dim3(G3, 6), 256, 0, stream>>>(jobs);

    // 1) Pb = bf16(emb @ w_Wih^T + w_bih), gate-interleaved  [50000 x 768]
    gemm_mfma<7, true><<<dim3((VOCAB + 127) / 128, 4), 512, 0, stream>>>(
        emb, WihB_w, w_bih, (unsigned*)Pb, VOCAB, EDIM);

    // 2) Word-level GRU (gather): 4096 seqs x 32 steps -> sent_hB
    gru_mfma<<<NSEQ1 / 16, 512, 0, stream>>>(
        idx, Pb, WhhB_w, w_bhh, sent_hB,
        nullptr, nullptr, nullptr, nullptr, nullptr, T1);

    // 3) gx2b = bf16(sent_h @ s_Wih^T + s_bih), interleaved  [4096 x 768]
    gemm_mfma<8, false><<<dim3(NSEQ1 / 128, 4), 512, 0, stream>>>(
        sent_hB, sWihB, s_bih, (unsigned*)gx2b, NSEQ1, HDIM);

    // 4) Sentence-level GRU (dense) + fused r_stars MLP -> out[16..271]
    gru_mfma<<<NSEQ2 / 16, 512, 0, stream>>>(
        nullptr, gx2b, sWhhB, s_bhh, rev_hB,
        rfc_W1, rfc_b1, rfc_W2, rfc_b2, out + 16, T2);

    // 5) gx3b = bf16(rev_h @ r_Wih^T + r_bih), interleaved  [256 x 768]
    gemm_mfma<8, false><<<dim3(2, 4), 512, 0, stream>>>(
        rev_hB, rWihB, r_bih, (unsigned*)gx3b, NSEQ2, HDIM);

    // 6) Review-level GRU (dense) + fused b_stars MLP -> out[0..15]
    gru_mfma<<<1, 512, 0, stream>>>(
        nullptr, gx3b, rWhhB, r_bhh, nullptr,
        pfc_W1, pfc_b1, pfc_W2, pfc_b2, out, T3);
}